// Round 10
// baseline (129.387 us; speedup 1.0000x reference)
//
#include <hip/hip_runtime.h>

// Problem constants
#define B_SIZE 16384
#define D_DIM  1024
#define T_DIM  128
#define VLn    12
#define BM     32             // rows per block
#define NCHUNK 16             // K chunks of 64
#define GRID   (B_SIZE / BM)  // 512
#define ASTR   66             // LDS A row stride (floats): 2-way banks on both patterns
#define ABUF   8448           // 32*66*4 bytes per A buffer
#define SL_STRIDE 132

typedef _Float16 half8  __attribute__((ext_vector_type(8)));
typedef __fp16   fp16x2 __attribute__((ext_vector_type(2)));
typedef float    f32x4  __attribute__((ext_vector_type(4)));

union Pack16 { fp16x2 h[4]; uint4 u; half8 v; };
union Frag   { uint4 u; half8 h; };

__device__ __forceinline__ uint4 pack8u(float4 v0, float4 v1) {
    Pack16 un;
    un.h[0] = __builtin_amdgcn_cvt_pkrtz(v0.x, v0.y);
    un.h[1] = __builtin_amdgcn_cvt_pkrtz(v0.z, v0.w);
    un.h[2] = __builtin_amdgcn_cvt_pkrtz(v1.x, v1.y);
    un.h[3] = __builtin_amdgcn_cvt_pkrtz(v1.z, v1.w);
    return un.u;
}
__device__ __forceinline__ half8 pack8h(float4 v0, float4 v1) {
    Pack16 un;
    un.h[0] = __builtin_amdgcn_cvt_pkrtz(v0.x, v0.y);
    un.h[1] = __builtin_amdgcn_cvt_pkrtz(v0.z, v0.w);
    un.h[2] = __builtin_amdgcn_cvt_pkrtz(v1.x, v1.y);
    un.h[3] = __builtin_amdgcn_cvt_pkrtz(v1.z, v1.w);
    return un.v;
}

// W fp32 [128][1024] -> f16, swizzled into MFMA B-fragment order:
// unit j (16 B = 8 f16): kc=j>>10, g=(j&1023)>>6 (g = ks*8+CT), lane=j&63;
// holds W[n = CT*16 + (lane&15)][k = kc*64 + ks*32 + (lane>>4)*8 .. +8].
__global__ __launch_bounds__(256)
void conv_w(const float* __restrict__ W, uint4* __restrict__ Wf) {
    const int j    = blockIdx.x * 256 + threadIdx.x;   // 0..16383
    const int kc   = j >> 10;
    const int r    = j & 1023;
    const int g    = r >> 6;
    const int lane = r & 63;
    const int n = (g & 7) * 16 + (lane & 15);
    const int k = kc * 64 + (g >> 3) * 32 + ((lane >> 4) << 3);
    const float* src = W + (size_t)n * D_DIM + k;
    Wf[j] = pack8u(*(const float4*)src, *(const float4*)(src + 4));
}

// 512 blocks x 256 threads (4 waves) = 2 blocks/CU.
// A: DENSE global loads (wave-instr = 8 rows x 128 B fully-consumed lines),
//    transposed to fragment order via LDS (f32, stride 66, 2-way banks).
//    2-deep register prefetch so ds_write consumes iteration-old data.
// B: dense 16 B/lane from pre-swizzled Wf, 2-chunk register pipeline.
__global__ __launch_bounds__(256, 2)
void qloss_kernel(const float* __restrict__ emb,
                  const uint4* __restrict__ Wf,
                  const float* __restrict__ bias,
                  const int*   __restrict__ didx,
                  const int*   __restrict__ dmsk,
                  float*       __restrict__ out)
{
    __shared__ __align__(16) unsigned char smem[2 * ABUF + 16];
    float* sL   = (float*)smem;                    // [32][132] f32 epilogue alias
    float* sRed = (float*)(smem + 2 * ABUF);

    const int t    = threadIdx.x;
    const int w    = t >> 6;
    const int lane = t & 63;
    const int m15  = lane & 15;
    const int quad = lane >> 4;
    const int r0   = blockIdx.x * BM;

    // --- dense A staging map ---
    // thread t: row = t>>3 (0..31), col floats = (t&7)*4 + 32*i, i=0,1.
    // Per wave-instr: 8 rows x 128 B contiguous (full cache lines).
    const int arow = t >> 3;
    const int acol = (t & 7) * 4;
    const float* aG = emb + (size_t)(r0 + arow) * D_DIM + acol;
    // LDS write addr (f32 idx): arow*66 + acol + 32*i  -> banks 2-way (free)
    float* aL = (float*)smem + arow * ASTR + acol;

    // frag read base (f32 idx): (mt*16+m15)*66 + ks*32 + quad*8  -> 2-way
    const int frBase = m15 * ASTR + quad * 8;

    // B-frag (ks, j): Wf[kc*1024 + (ks*8 + 2w+j)*64 + lane]
    const uint4* bP = Wf + (size_t)(2 * w) * 64 + lane;

    f32x4 acc[2][2];
#pragma unroll
    for (int mt = 0; mt < 2; ++mt)
#pragma unroll
        for (int ct = 0; ct < 2; ++ct) acc[mt][ct] = (f32x4){0.f, 0.f, 0.f, 0.f};

    Frag bc[4], bn1[4], bn2[4];
    float4 a1v0, a1v1, a2v0, a2v1;

    // ---- prologue ----
    {
        const float4 v0 = *(const float4*)(aG);        // chunk 0
        const float4 v1 = *(const float4*)(aG + 32);
        a1v0 = *(const float4*)(aG + 64);              // chunk 1
        a1v1 = *(const float4*)(aG + 96);
#pragma unroll
        for (int ks = 0; ks < 2; ++ks)
#pragma unroll
            for (int j = 0; j < 2; ++j) {
                bc[ks * 2 + j].u  = bP[(size_t)(ks * 8 + j) * 64];
                bn1[ks * 2 + j].u = bP[(size_t)1 * 1024 + (ks * 8 + j) * 64];
            }
        *(float4*)(aL)      = v0;                      // buf0
        *(float4*)(aL + 32) = v1;
    }
    __syncthreads();

#pragma unroll
    for (int kc = 0; kc < NCHUNK; ++kc) {
        float* bufC = (float*)(smem + (kc & 1) * ABUF);
        float* bufN = (float*)(smem + ((kc & 1) ^ 1) * ABUF);

        // issue chunk kc+2 loads (arrive during next iteration)
        if (kc + 2 < NCHUNK) {
            a2v0 = *(const float4*)(aG + (kc + 2) * 64);
            a2v1 = *(const float4*)(aG + (kc + 2) * 64 + 32);
#pragma unroll
            for (int ks = 0; ks < 2; ++ks)
#pragma unroll
                for (int j = 0; j < 2; ++j)
                    bn2[ks * 2 + j].u = bP[(size_t)(kc + 2) * 1024 + (ks * 8 + j) * 64];
        }

        // compute chunk kc: A frags via ds_read_b128 pairs + pack, B from regs
#pragma unroll
        for (int ks = 0; ks < 2; ++ks) {
#pragma unroll
            for (int mt = 0; mt < 2; ++mt) {
                const float* fp = bufC + mt * 16 * ASTR + frBase + ks * 32;
                const float4 lo = *(const float4*)(fp);
                const float4 hi = *(const float4*)(fp + 4);
                const half8 a = pack8h(lo, hi);
                acc[mt][0] = __builtin_amdgcn_mfma_f32_16x16x32_f16(a, bc[ks * 2 + 0].h, acc[mt][0], 0, 0, 0);
                acc[mt][1] = __builtin_amdgcn_mfma_f32_16x16x32_f16(a, bc[ks * 2 + 1].h, acc[mt][1], 0, 0, 0);
            }
        }

        // stage A(kc+1) from regs loaded LAST iteration (no vmcnt stall)
        if (kc + 1 < NCHUNK) {
            float* wp = bufN + arow * ASTR + acol;
            *(float4*)(wp)      = a1v0;
            *(float4*)(wp + 32) = a1v1;
        }
        __syncthreads();

        // rotate pipelines
        a1v0 = a2v0; a1v1 = a2v1;
#pragma unroll
        for (int q = 0; q < 4; ++q) { bc[q] = bn1[q]; bn1[q] = bn2[q]; }
    }

    // ---- epilogue: logits -> sL (aliases A buffers; all reads done) ----
    const int CT0 = w * 2;
    const float b0v = bias[CT0 * 16 + m15];
    const float b1v = bias[(CT0 + 1) * 16 + m15];
#pragma unroll
    for (int mt = 0; mt < 2; ++mt)
#pragma unroll
        for (int i = 0; i < 4; ++i) {
            const int row = mt * 16 + quad * 4 + i;
            sL[row * SL_STRIDE + CT0 * 16 + m15]       = acc[mt][0][i] + b0v;
            sL[row * SL_STRIDE + (CT0 + 1) * 16 + m15] = acc[mt][1][i] + b1v;
        }
    __syncthreads();

    // softmax: 8 threads/row, 16 cols each
    {
        const int row = t >> 3, s = t & 7;
        float* base = &sL[row * SL_STRIDE + s * 16];
        float v[16];
#pragma unroll
        for (int j = 0; j < 4; ++j) *(float4*)&v[j * 4] = *(const float4*)(base + j * 4);
        float m = -1e30f;
#pragma unroll
        for (int j = 0; j < 16; ++j) m = fmaxf(m, v[j]);
#pragma unroll
        for (int off = 1; off < 8; off <<= 1) m = fmaxf(m, __shfl_xor(m, off));
        float ssum = 0.f;
#pragma unroll
        for (int j = 0; j < 16; ++j) { v[j] = __expf(v[j] - m); ssum += v[j]; }
#pragma unroll
        for (int off = 1; off < 8; off <<= 1) ssum += __shfl_xor(ssum, off);
        const float inv = 1.0f / ssum;
#pragma unroll
        for (int j = 0; j < 16; ++j) v[j] *= inv;
#pragma unroll
        for (int j = 0; j < 4; ++j) *(float4*)(base + j * 4) = *(const float4*)&v[j * 4];
    }
    __syncthreads();

    // gather: 384 (row, j) entries; block partial -> one atomicAdd
    float p = 0.f;
#pragma unroll
    for (int i = t; i < BM * VLn; i += 256) {
        const int gi  = r0 * VLn + i;
        const int row = i / VLn;
        const int idx = didx[gi];
        const int mk  = dmsk[gi];
        p += mk ? sL[row * SL_STRIDE + idx] : 0.f;
    }
#pragma unroll
    for (int off = 1; off < 64; off <<= 1) p += __shfl_xor(p, off);
    if (lane == 0) sRed[w] = p;
    __syncthreads();
    if (t == 0)
        atomicAdd(out, (sRed[0] + sRed[1] + sRed[2] + sRed[3]) * (1.0f / 65536.0f));
}

extern "C" void kernel_launch(void* const* d_in, const int* in_sizes, int n_in,
                              void* d_out, int out_size, void* d_ws, size_t ws_size,
                              hipStream_t stream) {
    const float* emb  = (const float*)d_in[0];
    const float* W    = (const float*)d_in[1];
    const float* bias = (const float*)d_in[2];
    const int*   didx = (const int*)d_in[3];
    const int*   dmsk = (const int*)d_in[4];
    float* out = (float*)d_out;

    uint4* Wf = (uint4*)d_ws;   // 256 KB swizzled f16 W

    hipMemsetAsync(out, 0, sizeof(float), stream);
    conv_w<<<64, 256, 0, stream>>>(W, Wf);
    qloss_kernel<<<GRID, 256, 0, stream>>>(emb, Wf, bias, didx, dmsk, out);
}

// Round 11
// 114.300 us; speedup vs baseline: 1.1320x; 1.1320x over previous
//
#include <hip/hip_runtime.h>

// Problem constants
#define B_SIZE 16384
#define D_DIM  1024
#define T_DIM  128
#define VLn    12
#define BM     16              // rows per block (one m-tile)
#define BK     256             // K per chunk -> 1 KB per row per chunk (linear DMA)
#define NCHUNK 4
#define GRID   (B_SIZE / BM)   // 1024
#define AROWF  258             // LDS A row stride in floats (256 + 2 pad -> 4-way banks)
#define AROWB  1032            // bytes
#define ABUFB  (BM * AROWB)    // 16512 B per buffer
#define SLSTR  132

typedef _Float16 half8  __attribute__((ext_vector_type(8)));
typedef __fp16   fp16x2 __attribute__((ext_vector_type(2)));
typedef float    f32x4  __attribute__((ext_vector_type(4)));

union Pack16 { fp16x2 h[4]; uint4 u; half8 v; };
union Frag   { uint4 u; half8 h; };

__device__ __forceinline__ uint4 pack8u(float4 v0, float4 v1) {
    Pack16 un;
    un.h[0] = __builtin_amdgcn_cvt_pkrtz(v0.x, v0.y);
    un.h[1] = __builtin_amdgcn_cvt_pkrtz(v0.z, v0.w);
    un.h[2] = __builtin_amdgcn_cvt_pkrtz(v1.x, v1.y);
    un.h[3] = __builtin_amdgcn_cvt_pkrtz(v1.z, v1.w);
    return un.u;
}
// build f16 A-frag from 8 consecutive f32 in LDS (8-B aligned)
__device__ __forceinline__ half8 pack8f(const float* fp) {
    const float2 a = ((const float2*)fp)[0];
    const float2 b = ((const float2*)fp)[1];
    const float2 c = ((const float2*)fp)[2];
    const float2 d = ((const float2*)fp)[3];
    Pack16 un;
    un.h[0] = __builtin_amdgcn_cvt_pkrtz(a.x, a.y);
    un.h[1] = __builtin_amdgcn_cvt_pkrtz(b.x, b.y);
    un.h[2] = __builtin_amdgcn_cvt_pkrtz(c.x, c.y);
    un.h[3] = __builtin_amdgcn_cvt_pkrtz(d.x, d.y);
    return un.v;
}

// async global->LDS DMA, 16 B/lane: LDS dest = wave-uniform base + lane*16
__device__ __forceinline__ void dma16(const float* g, void* l) {
    __builtin_amdgcn_global_load_lds(
        (__attribute__((address_space(1))) void*)g,
        (__attribute__((address_space(3))) void*)l, 16, 0, 0);
}

// W fp32 [128][1024] -> f16, swizzled into MFMA B-fragment order (verified):
// unit j: kcW=j>>10, g=(j&1023)>>6 (g = ksW*8+CT), lane=j&63;
// holds W[n = CT*16 + (lane&15)][k = kcW*64 + ksW*32 + (lane>>4)*8 .. +8].
__global__ __launch_bounds__(256)
void conv_w(const float* __restrict__ W, uint4* __restrict__ Wf) {
    const int j    = blockIdx.x * 256 + threadIdx.x;   // 0..16383
    const int kc   = j >> 10;
    const int r    = j & 1023;
    const int g    = r >> 6;
    const int lane = r & 63;
    const int n = (g & 7) * 16 + (lane & 15);
    const int k = kc * 64 + (g >> 3) * 32 + ((lane >> 4) << 3);
    const float* src = W + (size_t)n * D_DIM + k;
    Wf[j] = pack8u(*(const float4*)src, *(const float4*)(src + 4));
}

// 1024 blocks x 256 threads (4 waves), 2 blocks/CU. Block = 16 rows x 128
// cols x full K. Wave w owns col-tiles {2w, 2w+1}.
// A: async DMA (global_load_lds width 16) of linear 1 KB row-pieces into
//    double-buffered LDS; one barrier per chunk; DMA covered by compute.
// B: register prefetch (1 chunk ahead) from pre-swizzled Wf; the chunk
//    barrier's vmcnt(0) drain makes it zero-wait at use.
__global__ __launch_bounds__(256, 2)
void qloss_kernel(const float* __restrict__ emb,
                  const uint4* __restrict__ Wf,
                  const float* __restrict__ bias,
                  const int*   __restrict__ didx,
                  const int*   __restrict__ dmsk,
                  float*       __restrict__ out)
{
    __shared__ __align__(16) unsigned char smem[2 * ABUFB + 16];   // 33040 B
    float* sL   = (float*)smem;                    // [16][132] epilogue alias
    float* sRed = (float*)(smem + 2 * ABUFB);

    const int t    = threadIdx.x;
    const int w    = t >> 6;
    const int lane = t & 63;
    const int m15  = lane & 15;
    const int quad = lane >> 4;
    const int r0   = blockIdx.x * BM;

    // DMA: wave w stages rows 4w..4w+3; per row one call (64 lanes x 16 B = 1 KB)
    const float* aG0 = emb + (size_t)(r0 + 4 * w) * D_DIM + lane * 4;

    // B frag for global k-step s (32 k each), col-tile ct:
    //   Wf[(s>>1)*1024 + ((s&1)*8 + ct)*64 + lane]
    const uint4* bP = Wf + lane;
    const int CT0 = 2 * w;

    f32x4 acc[2];
    acc[0] = (f32x4){0.f, 0.f, 0.f, 0.f};
    acc[1] = (f32x4){0.f, 0.f, 0.f, 0.f};

    Frag bc[16], bn[16];

    // ---- prologue: DMA chunk 0 -> buf0; B(chunk 0) -> bc ----
#pragma unroll
    for (int r = 0; r < 4; ++r)
        dma16(aG0 + (size_t)r * D_DIM, smem + (4 * w + r) * AROWB);
#pragma unroll
    for (int ks = 0; ks < 8; ++ks) {
        const int s = ks;                     // chunk 0
#pragma unroll
        for (int j = 0; j < 2; ++j)
            bc[ks * 2 + j].u = bP[(size_t)(s >> 1) * 1024 + ((s & 1) * 8 + CT0 + j) * 64];
    }
    __syncthreads();   // drains DMA(0) + B(0)

#pragma unroll
    for (int kc = 0; kc < NCHUNK; ++kc) {
        const unsigned char* bufC = smem + (kc & 1) * ABUFB;
        unsigned char*       bufN = (unsigned char*)smem + ((kc & 1) ^ 1) * ABUFB;

        // issue next chunk's DMA + B loads first (covered by compute below,
        // drained by the barrier at the end of this iteration)
        if (kc + 1 < NCHUNK) {
#pragma unroll
            for (int r = 0; r < 4; ++r)
                dma16(aG0 + (size_t)r * D_DIM + (kc + 1) * BK,
                      bufN + (4 * w + r) * AROWB);
#pragma unroll
            for (int ks = 0; ks < 8; ++ks) {
                const int s = (kc + 1) * 8 + ks;
#pragma unroll
                for (int j = 0; j < 2; ++j)
                    bn[ks * 2 + j].u =
                        bP[(size_t)(s >> 1) * 1024 + ((s & 1) * 8 + CT0 + j) * 64];
            }
        }

        // compute chunk kc: 8 k-steps x 2 col-tiles
#pragma unroll
        for (int ks = 0; ks < 8; ++ks) {
            const float* fp = (const float*)bufC + m15 * AROWF + ks * 32 + quad * 8;
            const half8 a = pack8f(fp);
            acc[0] = __builtin_amdgcn_mfma_f32_16x16x32_f16(a, bc[ks * 2 + 0].h, acc[0], 0, 0, 0);
            acc[1] = __builtin_amdgcn_mfma_f32_16x16x32_f16(a, bc[ks * 2 + 1].h, acc[1], 0, 0, 0);
        }
        __syncthreads();   // DMA(kc+1) complete; bufC free for reuse next iter

#pragma unroll
        for (int q = 0; q < 16; ++q) bc[q] = bn[q];
    }

    // ---- epilogue: logits -> sL (aliases buf0; all reads done) ----
    const float b0v = bias[CT0 * 16 + m15];
    const float b1v = bias[(CT0 + 1) * 16 + m15];
#pragma unroll
    for (int i = 0; i < 4; ++i) {
        const int row = quad * 4 + i;
        sL[row * SLSTR + CT0 * 16 + m15]       = acc[0][i] + b0v;
        sL[row * SLSTR + (CT0 + 1) * 16 + m15] = acc[1][i] + b1v;
    }
    __syncthreads();

    // softmax: 16 threads/row, 8 cols each (xor 1,2,4,8 stays in 16-group)
    {
        const int row = t >> 4, s = t & 15;
        float* base = &sL[row * SLSTR + s * 8];
        float v[8];
        *(float4*)&v[0] = *(const float4*)(base);
        *(float4*)&v[4] = *(const float4*)(base + 4);
        float m = -1e30f;
#pragma unroll
        for (int j = 0; j < 8; ++j) m = fmaxf(m, v[j]);
#pragma unroll
        for (int off = 1; off < 16; off <<= 1) m = fmaxf(m, __shfl_xor(m, off));
        float ssum = 0.f;
#pragma unroll
        for (int j = 0; j < 8; ++j) { v[j] = __expf(v[j] - m); ssum += v[j]; }
#pragma unroll
        for (int off = 1; off < 16; off <<= 1) ssum += __shfl_xor(ssum, off);
        const float inv = 1.0f / ssum;
#pragma unroll
        for (int j = 0; j < 8; ++j) v[j] *= inv;
        *(float4*)(base)     = *(const float4*)&v[0];
        *(float4*)(base + 4) = *(const float4*)&v[4];
    }
    __syncthreads();

    // gather: 192 (row, j) entries; block partial -> one atomicAdd
    float p = 0.f;
    if (t < BM * VLn) {
        const int gi  = r0 * VLn + t;
        const int row = t / VLn;
        const int idx = didx[gi];
        const int mk  = dmsk[gi];
        p = mk ? sL[row * SLSTR + idx] : 0.f;
    }
#pragma unroll
    for (int off = 1; off < 64; off <<= 1) p += __shfl_xor(p, off);
    if (lane == 0) sRed[w] = p;
    __syncthreads();
    if (t == 0)
        atomicAdd(out, (sRed[0] + sRed[1] + sRed[2] + sRed[3]) * (1.0f / 65536.0f));
}

extern "C" void kernel_launch(void* const* d_in, const int* in_sizes, int n_in,
                              void* d_out, int out_size, void* d_ws, size_t ws_size,
                              hipStream_t stream) {
    const float* emb  = (const float*)d_in[0];
    const float* W    = (const float*)d_in[1];
    const float* bias = (const float*)d_in[2];
    const int*   didx = (const int*)d_in[3];
    const int*   dmsk = (const int*)d_in[4];
    float* out = (float*)d_out;

    uint4* Wf = (uint4*)d_ws;   // 256 KB swizzled f16 W

    hipMemsetAsync(out, 0, sizeof(float), stream);
    conv_w<<<64, 256, 0, stream>>>(W, Wf);
    qloss_kernel<<<GRID, 256, 0, stream>>>(emb, Wf, bias, didx, dmsk, out);
}